// Round 1
// baseline (722.666 us; speedup 1.0000x reference)
//
#include <hip/hip_runtime.h>

// GraphEmbedNet: 3-layer GCN, N=50000, E=800000, F=128/128/64, fp32 throughout.
// Strategy: build CSR by target node once per call (histogram + 1-block scan +
// cursor scatter, self-loop in slot 0), then per layer: tiled fp32 GEMM
// (h @ W^T) followed by atomic-free wave-per-node weighted gather + bias+relu.

#define K_DIM 128

// ---------------- CSR build ----------------

__global__ void degree_kernel(const int* __restrict__ col, const float* __restrict__ ew,
                              float* __restrict__ degw, int* __restrict__ cnt, int E) {
    int e = blockIdx.x * blockDim.x + threadIdx.x;
    if (e < E) {
        int c = col[e];
        atomicAdd(&degw[c], ew[e]);
        atomicAdd(&cnt[c], 1);
    }
}

// in-place: degw[i] <- 1/sqrt(degw[i] + 1)   (self-loop weight 1; deg >= 1 always)
__global__ void dinv_kernel(float* degw, int n) {
    int i = blockIdx.x * blockDim.x + threadIdx.x;
    if (i < n) degw[i] = rsqrtf(degw[i] + 1.0f);
}

// single block, 1024 threads: exclusive scan of (cnt[i]+1); writes offsets,
// cursors (past the self-loop slot), and the self-loop CSR entry per node.
__global__ void scan_kernel(const int* __restrict__ cnt, const float* __restrict__ dinv,
                            int* __restrict__ offs, int* __restrict__ cursor,
                            int* __restrict__ csr_src, float* __restrict__ csr_w,
                            int n, int e, int ch) {
    __shared__ int sums[1024];
    const int t = threadIdx.x;
    const int lo = t * ch;
    const int hi = min(lo + ch, n);
    int s = 0;
    for (int i = lo; i < hi; ++i) s += cnt[i] + 1;
    sums[t] = s;
    __syncthreads();
    for (int off = 1; off < 1024; off <<= 1) {
        int v = (t >= off) ? sums[t - off] : 0;
        __syncthreads();
        sums[t] += v;
        __syncthreads();
    }
    int running = (t == 0) ? 0 : sums[t - 1];
    for (int i = lo; i < hi; ++i) {
        offs[i] = running;
        cursor[i] = running + 1;        // slot 0 = self-loop, cursor past it
        csr_src[running] = i;
        float d = dinv[i];
        csr_w[running] = d * d;         // dinv[i] * 1.0 * dinv[i]
        running += cnt[i] + 1;
    }
    if (t == 0) offs[n] = n + e;
}

__global__ void fill_kernel(const int* __restrict__ row, const int* __restrict__ col,
                            const float* __restrict__ ew, const float* __restrict__ dinv,
                            int* __restrict__ cursor, int* __restrict__ csr_src,
                            float* __restrict__ csr_w, int E) {
    int e = blockIdx.x * blockDim.x + threadIdx.x;
    if (e < E) {
        int c = col[e], r = row[e];
        float nw = dinv[r] * ew[e] * dinv[c];
        int pos = atomicAdd(&cursor[c], 1);
        csr_src[pos] = r;
        csr_w[pos] = nw;
    }
}

// ---------------- fp32 tiled GEMM: C[n][o] = sum_k A[n][k] * W[o][k] ----------------
// A: [nrows, 128] row-major; W: [BN, 128] row-major; C: [nrows, BN].
// Block tile BM x BN, BK=16, micro-tile 8x8 per thread.

template <int BM, int BN>
__global__ void gemm_kernel(const float* __restrict__ A, const float* __restrict__ W,
                            float* __restrict__ C, int nrows) {
    constexpr int BK = 16;
    constexpr int TY = BM / 8;
    constexpr int TX = BN / 8;
    constexpr int NT = TY * TX;
    __shared__ float As[BK][BM + 4];
    __shared__ float Bs[BK][BN + 4];

    const int tid = threadIdx.x;
    const int tx = tid % TX;
    const int ty = tid / TX;
    const int row0 = blockIdx.x * BM;

    float acc[8][8] = {};

    for (int k0 = 0; k0 < K_DIM; k0 += BK) {
        // stage A chunk: BM rows x BK k  (BM*4 float4 loads)
        constexpr int ITA = (BM * 4) / NT;
#pragma unroll
        for (int p = 0; p < ITA; ++p) {
            int lin = tid + p * NT;           // 0 .. BM*4-1
            int r = lin >> 2;
            int kq = lin & 3;
            int gr = row0 + r;
            if (gr > nrows - 1) gr = nrows - 1;
            const float4 v = *(const float4*)(A + (size_t)gr * K_DIM + k0 + kq * 4);
            As[kq * 4 + 0][r] = v.x;
            As[kq * 4 + 1][r] = v.y;
            As[kq * 4 + 2][r] = v.z;
            As[kq * 4 + 3][r] = v.w;
        }
        // stage B chunk: BN outs x BK k
        constexpr int ITB = (BN * 4) / NT;
#pragma unroll
        for (int p = 0; p < ITB; ++p) {
            int lin = tid + p * NT;
            int o = lin >> 2;
            int kq = lin & 3;
            const float4 v = *(const float4*)(W + (size_t)o * K_DIM + k0 + kq * 4);
            Bs[kq * 4 + 0][o] = v.x;
            Bs[kq * 4 + 1][o] = v.y;
            Bs[kq * 4 + 2][o] = v.z;
            Bs[kq * 4 + 3][o] = v.w;
        }
        __syncthreads();
#pragma unroll
        for (int kk = 0; kk < BK; ++kk) {
            float a[8], b[8];
#pragma unroll
            for (int i = 0; i < 8; ++i) a[i] = As[kk][ty * 8 + i];
#pragma unroll
            for (int j = 0; j < 8; ++j) b[j] = Bs[kk][tx * 8 + j];
#pragma unroll
            for (int i = 0; i < 8; ++i)
#pragma unroll
                for (int j = 0; j < 8; ++j)
                    acc[i][j] = fmaf(a[i], b[j], acc[i][j]);
        }
        __syncthreads();
    }

#pragma unroll
    for (int i = 0; i < 8; ++i) {
        int gr = row0 + ty * 8 + i;
        if (gr < nrows) {
#pragma unroll
            for (int j = 0; j < 8; j += 4) {
                float4 v = make_float4(acc[i][j], acc[i][j + 1], acc[i][j + 2], acc[i][j + 3]);
                *(float4*)(C + (size_t)gr * BN + tx * 8 + j) = v;
            }
        }
    }
}

// ---------------- aggregation: out[i] = relu(bias + sum_e w_e * m[src_e]) ----------------
// one wave per node; D=128: lane handles f and f+64; D=64: lane handles f.

template <int D>
__global__ __launch_bounds__(256) void agg_kernel(
    const float* __restrict__ m, const int* __restrict__ offs,
    const int* __restrict__ src, const float* __restrict__ wgt,
    const float* __restrict__ bias, float* __restrict__ out, int n) {
    const int wid = threadIdx.x >> 6;
    const int lane = threadIdx.x & 63;
    const int node = (blockIdx.x << 2) + wid;
    if (node >= n) return;
    const int beg = offs[node];
    const int end = offs[node + 1];
    float acc0 = 0.f, acc1 = 0.f;
    int k = beg;
    for (; k + 2 <= end; k += 2) {
        int s0 = src[k], s1 = src[k + 1];
        float w0 = wgt[k], w1 = wgt[k + 1];
        const float* r0 = m + (size_t)s0 * D;
        const float* r1 = m + (size_t)s1 * D;
        float v0 = r0[lane], v1 = r1[lane];
        acc0 = fmaf(w0, v0, acc0);
        acc0 = fmaf(w1, v1, acc0);
        if (D == 128) {
            float u0 = r0[lane + 64], u1 = r1[lane + 64];
            acc1 = fmaf(w0, u0, acc1);
            acc1 = fmaf(w1, u1, acc1);
        }
    }
    if (k < end) {
        int s0 = src[k];
        float w0 = wgt[k];
        const float* r0 = m + (size_t)s0 * D;
        acc0 = fmaf(w0, r0[lane], acc0);
        if (D == 128) acc1 = fmaf(w0, r0[lane + 64], acc1);
    }
    float* orow = out + (size_t)node * D;
    orow[lane] = fmaxf(acc0 + bias[lane], 0.f);
    if (D == 128) orow[lane + 64] = fmaxf(acc1 + bias[lane + 64], 0.f);
}

// ---------------- launch ----------------

extern "C" void kernel_launch(void* const* d_in, const int* in_sizes, int n_in,
                              void* d_out, int out_size, void* d_ws, size_t ws_size,
                              hipStream_t stream) {
    const float* x  = (const float*)d_in[0];
    const int*   ei = (const int*)d_in[1];   // [2, E] int32
    const float* ew = (const float*)d_in[2];
    const float* W1 = (const float*)d_in[3];
    const float* b1 = (const float*)d_in[4];
    const float* W2 = (const float*)d_in[5];
    const float* b2 = (const float*)d_in[6];
    const float* W3 = (const float*)d_in[7];
    const float* b3 = (const float*)d_in[8];
    float* out = (float*)d_out;

    const int N = in_sizes[0] / K_DIM;      // 50000
    const int E = in_sizes[2];              // 800000
    const int* row = ei;                    // edge_index[0] (source)
    const int* col = ei + E;                // edge_index[1] (target / aggregation)

    // workspace layout (~59 MB)
    float* m_buf  = (float*)d_ws;                              // N*128
    float* h_buf  = m_buf + (size_t)N * K_DIM;                 // N*128
    int*   csr_src = (int*)(h_buf + (size_t)N * K_DIM);        // N+E
    float* csr_w   = (float*)(csr_src + (size_t)(N + E));      // N+E
    int*   offs    = (int*)(csr_w + (size_t)(N + E));          // N+1
    int*   cursor  = offs + (N + 1);                           // N
    float* degw    = (float*)(cursor + N);                     // N (becomes dinv in place)
    int*   cnt     = (int*)(degw + N);                         // N

    hipMemsetAsync(degw, 0, (size_t)2 * N * sizeof(float), stream);  // degw + cnt

    degree_kernel<<<(E + 255) / 256, 256, 0, stream>>>(col, ew, degw, cnt, E);
    dinv_kernel<<<(N + 255) / 256, 256, 0, stream>>>(degw, N);
    const int ch = (N + 1023) / 1024;
    scan_kernel<<<1, 1024, 0, stream>>>(cnt, degw, offs, cursor, csr_src, csr_w, N, E, ch);
    fill_kernel<<<(E + 255) / 256, 256, 0, stream>>>(row, col, ew, degw, cursor,
                                                     csr_src, csr_w, E);

    const int gemm_blocks = (N + 63) / 64;
    const int agg_blocks = (N + 3) / 4;

    // layer 1: m = x @ W1^T ; h = relu(agg(m) + b1)
    gemm_kernel<64, 128><<<gemm_blocks, 128, 0, stream>>>(x, W1, m_buf, N);
    agg_kernel<128><<<agg_blocks, 256, 0, stream>>>(m_buf, offs, csr_src, csr_w, b1, h_buf, N);
    // layer 2
    gemm_kernel<64, 128><<<gemm_blocks, 128, 0, stream>>>(h_buf, W2, m_buf, N);
    agg_kernel<128><<<agg_blocks, 256, 0, stream>>>(m_buf, offs, csr_src, csr_w, b2, h_buf, N);
    // layer 3: F_OUT=64, write d_out directly
    gemm_kernel<64, 64><<<gemm_blocks, 64, 0, stream>>>(h_buf, W3, m_buf, N);
    agg_kernel<64><<<agg_blocks, 256, 0, stream>>>(m_buf, offs, csr_src, csr_w, b3, out, N);
}

// Round 2
// 510.776 us; speedup vs baseline: 1.4148x; 1.4148x over previous
//
#include <hip/hip_runtime.h>

// GraphEmbedNet: 3-layer GCN, N=50000, E=800000, F=128/128/64, fp32 throughout.
// R1: single-block scan was 231us (one CU!). Replaced with 3-phase multi-block
// scan: block-reduce -> tiny scan of block sums -> block scan + write.

#define K_DIM 128
#define SCAN_B 256   // elements per scan block

// ---------------- CSR build ----------------

__global__ void degree_kernel(const int* __restrict__ col, const float* __restrict__ ew,
                              float* __restrict__ degw, int* __restrict__ cnt, int E) {
    int e = blockIdx.x * blockDim.x + threadIdx.x;
    if (e < E) {
        int c = col[e];
        atomicAdd(&degw[c], ew[e]);
        atomicAdd(&cnt[c], 1);
    }
}

// in-place: degw[i] <- 1/sqrt(degw[i] + 1)   (self-loop weight 1; deg >= 1 always)
__global__ void dinv_kernel(float* degw, int n) {
    int i = blockIdx.x * blockDim.x + threadIdx.x;
    if (i < n) degw[i] = rsqrtf(degw[i] + 1.0f);
}

// phase 1: per-block sum of (cnt[i]+1)
__global__ void block_reduce_kernel(const int* __restrict__ cnt, int* __restrict__ bsum, int n) {
    __shared__ int s[SCAN_B];
    const int t = threadIdx.x;
    const int i = blockIdx.x * SCAN_B + t;
    s[t] = (i < n) ? cnt[i] + 1 : 0;
    __syncthreads();
    for (int off = SCAN_B / 2; off > 0; off >>= 1) {
        if (t < off) s[t] += s[t + off];
        __syncthreads();
    }
    if (t == 0) bsum[blockIdx.x] = s[0];
}

// phase 2: single block, exclusive scan of nb (<=256) block sums in place
__global__ void bsum_scan_kernel(int* __restrict__ bsum, int nb) {
    __shared__ int s[SCAN_B];
    const int t = threadIdx.x;
    const int v = (t < nb) ? bsum[t] : 0;
    s[t] = v;
    __syncthreads();
    for (int off = 1; off < SCAN_B; off <<= 1) {
        int u = (t >= off) ? s[t - off] : 0;
        __syncthreads();
        s[t] += u;
        __syncthreads();
    }
    if (t < nb) bsum[t] = s[t] - v;   // exclusive
}

// phase 3: per-block exclusive scan + block prefix; write offs, cursor, and
// the self-loop CSR entry (slot 0 of each node's segment).
__global__ void scan_write_kernel(const int* __restrict__ cnt, const float* __restrict__ dinv,
                                  const int* __restrict__ bsum,
                                  int* __restrict__ offs, int* __restrict__ cursor,
                                  int* __restrict__ csr_src, float* __restrict__ csr_w,
                                  int n, int e) {
    __shared__ int s[SCAN_B];
    const int t = threadIdx.x;
    const int i = blockIdx.x * SCAN_B + t;
    const int v = (i < n) ? cnt[i] + 1 : 0;
    s[t] = v;
    __syncthreads();
    for (int off = 1; off < SCAN_B; off <<= 1) {
        int u = (t >= off) ? s[t - off] : 0;
        __syncthreads();
        s[t] += u;
        __syncthreads();
    }
    const int excl = s[t] - v + bsum[blockIdx.x];
    if (i < n) {
        offs[i] = excl;
        cursor[i] = excl + 1;          // slot 0 = self-loop, cursor past it
        csr_src[excl] = i;
        float d = dinv[i];
        csr_w[excl] = d * d;           // dinv[i] * 1.0 * dinv[i]
        if (i == n - 1) offs[n] = excl + v;   // = n + e
    }
}

__global__ void fill_kernel(const int* __restrict__ row, const int* __restrict__ col,
                            const float* __restrict__ ew, const float* __restrict__ dinv,
                            int* __restrict__ cursor, int* __restrict__ csr_src,
                            float* __restrict__ csr_w, int E) {
    int e = blockIdx.x * blockDim.x + threadIdx.x;
    if (e < E) {
        int c = col[e], r = row[e];
        float nw = dinv[r] * ew[e] * dinv[c];
        int pos = atomicAdd(&cursor[c], 1);
        csr_src[pos] = r;
        csr_w[pos] = nw;
    }
}

// ---------------- fp32 tiled GEMM: C[n][o] = sum_k A[n][k] * W[o][k] ----------------
// A: [nrows, 128] row-major; W: [BN, 128] row-major; C: [nrows, BN].
// Block tile BM x BN, BK=16, micro-tile 8x8 per thread.

template <int BM, int BN>
__global__ void gemm_kernel(const float* __restrict__ A, const float* __restrict__ W,
                            float* __restrict__ C, int nrows) {
    constexpr int BK = 16;
    constexpr int TY = BM / 8;
    constexpr int TX = BN / 8;
    constexpr int NT = TY * TX;
    __shared__ float As[BK][BM + 4];
    __shared__ float Bs[BK][BN + 4];

    const int tid = threadIdx.x;
    const int tx = tid % TX;
    const int ty = tid / TX;
    const int row0 = blockIdx.x * BM;

    float acc[8][8] = {};

    for (int k0 = 0; k0 < K_DIM; k0 += BK) {
        constexpr int ITA = (BM * 4) / NT;
#pragma unroll
        for (int p = 0; p < ITA; ++p) {
            int lin = tid + p * NT;           // 0 .. BM*4-1
            int r = lin >> 2;
            int kq = lin & 3;
            int gr = row0 + r;
            if (gr > nrows - 1) gr = nrows - 1;
            const float4 v = *(const float4*)(A + (size_t)gr * K_DIM + k0 + kq * 4);
            As[kq * 4 + 0][r] = v.x;
            As[kq * 4 + 1][r] = v.y;
            As[kq * 4 + 2][r] = v.z;
            As[kq * 4 + 3][r] = v.w;
        }
        constexpr int ITB = (BN * 4) / NT;
#pragma unroll
        for (int p = 0; p < ITB; ++p) {
            int lin = tid + p * NT;
            int o = lin >> 2;
            int kq = lin & 3;
            const float4 v = *(const float4*)(W + (size_t)o * K_DIM + k0 + kq * 4);
            Bs[kq * 4 + 0][o] = v.x;
            Bs[kq * 4 + 1][o] = v.y;
            Bs[kq * 4 + 2][o] = v.z;
            Bs[kq * 4 + 3][o] = v.w;
        }
        __syncthreads();
#pragma unroll
        for (int kk = 0; kk < BK; ++kk) {
            float a[8], b[8];
#pragma unroll
            for (int i = 0; i < 8; ++i) a[i] = As[kk][ty * 8 + i];
#pragma unroll
            for (int j = 0; j < 8; ++j) b[j] = Bs[kk][tx * 8 + j];
#pragma unroll
            for (int i = 0; i < 8; ++i)
#pragma unroll
                for (int j = 0; j < 8; ++j)
                    acc[i][j] = fmaf(a[i], b[j], acc[i][j]);
        }
        __syncthreads();
    }

#pragma unroll
    for (int i = 0; i < 8; ++i) {
        int gr = row0 + ty * 8 + i;
        if (gr < nrows) {
#pragma unroll
            for (int j = 0; j < 8; j += 4) {
                float4 v = make_float4(acc[i][j], acc[i][j + 1], acc[i][j + 2], acc[i][j + 3]);
                *(float4*)(C + (size_t)gr * BN + tx * 8 + j) = v;
            }
        }
    }
}

// ---------------- aggregation: out[i] = relu(bias + sum_e w_e * m[src_e]) ----------------
// one wave per node; D=128: lane handles f and f+64; D=64: lane handles f.

template <int D>
__global__ __launch_bounds__(256) void agg_kernel(
    const float* __restrict__ m, const int* __restrict__ offs,
    const int* __restrict__ src, const float* __restrict__ wgt,
    const float* __restrict__ bias, float* __restrict__ out, int n) {
    const int wid = threadIdx.x >> 6;
    const int lane = threadIdx.x & 63;
    const int node = (blockIdx.x << 2) + wid;
    if (node >= n) return;
    const int beg = offs[node];
    const int end = offs[node + 1];
    float acc0 = 0.f, acc1 = 0.f;
    int k = beg;
    for (; k + 2 <= end; k += 2) {
        int s0 = src[k], s1 = src[k + 1];
        float w0 = wgt[k], w1 = wgt[k + 1];
        const float* r0 = m + (size_t)s0 * D;
        const float* r1 = m + (size_t)s1 * D;
        float v0 = r0[lane], v1 = r1[lane];
        acc0 = fmaf(w0, v0, acc0);
        acc0 = fmaf(w1, v1, acc0);
        if (D == 128) {
            float u0 = r0[lane + 64], u1 = r1[lane + 64];
            acc1 = fmaf(w0, u0, acc1);
            acc1 = fmaf(w1, u1, acc1);
        }
    }
    if (k < end) {
        int s0 = src[k];
        float w0 = wgt[k];
        const float* r0 = m + (size_t)s0 * D;
        acc0 = fmaf(w0, r0[lane], acc0);
        if (D == 128) acc1 = fmaf(w0, r0[lane + 64], acc1);
    }
    float* orow = out + (size_t)node * D;
    orow[lane] = fmaxf(acc0 + bias[lane], 0.f);
    if (D == 128) orow[lane + 64] = fmaxf(acc1 + bias[lane + 64], 0.f);
}

// ---------------- launch ----------------

extern "C" void kernel_launch(void* const* d_in, const int* in_sizes, int n_in,
                              void* d_out, int out_size, void* d_ws, size_t ws_size,
                              hipStream_t stream) {
    const float* x  = (const float*)d_in[0];
    const int*   ei = (const int*)d_in[1];   // [2, E] int32
    const float* ew = (const float*)d_in[2];
    const float* W1 = (const float*)d_in[3];
    const float* b1 = (const float*)d_in[4];
    const float* W2 = (const float*)d_in[5];
    const float* b2 = (const float*)d_in[6];
    const float* W3 = (const float*)d_in[7];
    const float* b3 = (const float*)d_in[8];
    float* out = (float*)d_out;

    const int N = in_sizes[0] / K_DIM;      // 50000
    const int E = in_sizes[2];              // 800000
    const int* row = ei;                    // edge_index[0] (source)
    const int* col = ei + E;                // edge_index[1] (target / aggregation)

    const int nb = (N + SCAN_B - 1) / SCAN_B;   // scan blocks (196 <= 256)

    // workspace layout (~59 MB)
    float* m_buf  = (float*)d_ws;                              // N*128
    float* h_buf  = m_buf + (size_t)N * K_DIM;                 // N*128
    int*   csr_src = (int*)(h_buf + (size_t)N * K_DIM);        // N+E
    float* csr_w   = (float*)(csr_src + (size_t)(N + E));      // N+E
    int*   offs    = (int*)(csr_w + (size_t)(N + E));          // N+1
    int*   cursor  = offs + (N + 1);                           // N
    float* degw    = (float*)(cursor + N);                     // N (becomes dinv in place)
    int*   cnt     = (int*)(degw + N);                         // N
    int*   bsum    = cnt + N;                                  // nb

    hipMemsetAsync(degw, 0, (size_t)2 * N * sizeof(float), stream);  // degw + cnt

    degree_kernel<<<(E + 255) / 256, 256, 0, stream>>>(col, ew, degw, cnt, E);
    dinv_kernel<<<(N + 255) / 256, 256, 0, stream>>>(degw, N);
    block_reduce_kernel<<<nb, SCAN_B, 0, stream>>>(cnt, bsum, N);
    bsum_scan_kernel<<<1, SCAN_B, 0, stream>>>(bsum, nb);
    scan_write_kernel<<<nb, SCAN_B, 0, stream>>>(cnt, degw, bsum, offs, cursor,
                                                 csr_src, csr_w, N, E);
    fill_kernel<<<(E + 255) / 256, 256, 0, stream>>>(row, col, ew, degw, cursor,
                                                     csr_src, csr_w, E);

    const int gemm_blocks = (N + 63) / 64;
    const int agg_blocks = (N + 3) / 4;

    // layer 1: m = x @ W1^T ; h = relu(agg(m) + b1)
    gemm_kernel<64, 128><<<gemm_blocks, 128, 0, stream>>>(x, W1, m_buf, N);
    agg_kernel<128><<<agg_blocks, 256, 0, stream>>>(m_buf, offs, csr_src, csr_w, b1, h_buf, N);
    // layer 2
    gemm_kernel<64, 128><<<gemm_blocks, 128, 0, stream>>>(h_buf, W2, m_buf, N);
    agg_kernel<128><<<agg_blocks, 256, 0, stream>>>(m_buf, offs, csr_src, csr_w, b2, h_buf, N);
    // layer 3: F_OUT=64, write d_out directly
    gemm_kernel<64, 64><<<gemm_blocks, 64, 0, stream>>>(h_buf, W3, m_buf, N);
    agg_kernel<64><<<agg_blocks, 256, 0, stream>>>(m_buf, offs, csr_src, csr_w, b3, out, N);
}

// Round 3
// 451.082 us; speedup vs baseline: 1.6021x; 1.1323x over previous
//
#include <hip/hip_runtime.h>

// GraphEmbedNet: 3-layer GCN, N=50000, E=800000, F=128/128/64, fp32 throughout.
// R2: degree_kernel WRITE_SIZE showed 64B/atomic memory-side write-through ->
// atomic COUNT is the cost. Pack {cnt, weighted deg} into one u64 atomicAdd.
// CSR entries packed as int2{src, ew}; dinv[src] folded into GEMM epilogue,
// dinv[dst] folded into agg epilogue (fill needs no dinv gathers).

#define K_DIM 128
#define SCAN_B 256   // elements per scan block
#define FIXP 1048576.0f   // 2^20 fixed-point scale for weighted degree

// ---------------- CSR build ----------------

// one u64 atomic per edge: bits [40..) = count, [0..40) = sum(ew) * 2^20
__global__ void degree_kernel(const int* __restrict__ col, const float* __restrict__ ew,
                              unsigned long long* __restrict__ packed, int E) {
    int e = blockIdx.x * blockDim.x + threadIdx.x;
    if (e < E) {
        int c = col[e];
        unsigned long long add = (1ULL << 40) +
            (unsigned long long)(ew[e] * FIXP + 0.5f);
        atomicAdd(&packed[c], add);
    }
}

// unpack: dinv[i] = rsqrt(degw + 1), cnt[i] = count
__global__ void dinv_kernel(const unsigned long long* __restrict__ packed,
                            float* __restrict__ dinv, int* __restrict__ cnt, int n) {
    int i = blockIdx.x * blockDim.x + threadIdx.x;
    if (i < n) {
        unsigned long long p = packed[i];
        float degw = (float)(p & 0xFFFFFFFFFFULL) * (1.0f / FIXP);
        dinv[i] = rsqrtf(degw + 1.0f);
        cnt[i] = (int)(p >> 40);
    }
}

// phase 1: per-block sum of (cnt[i]+1)
__global__ void block_reduce_kernel(const int* __restrict__ cnt, int* __restrict__ bsum, int n) {
    __shared__ int s[SCAN_B];
    const int t = threadIdx.x;
    const int i = blockIdx.x * SCAN_B + t;
    s[t] = (i < n) ? cnt[i] + 1 : 0;
    __syncthreads();
    for (int off = SCAN_B / 2; off > 0; off >>= 1) {
        if (t < off) s[t] += s[t + off];
        __syncthreads();
    }
    if (t == 0) bsum[blockIdx.x] = s[0];
}

// phase 2: single block, exclusive scan of nb (<=256) block sums in place
__global__ void bsum_scan_kernel(int* __restrict__ bsum, int nb) {
    __shared__ int s[SCAN_B];
    const int t = threadIdx.x;
    const int v = (t < nb) ? bsum[t] : 0;
    s[t] = v;
    __syncthreads();
    for (int off = 1; off < SCAN_B; off <<= 1) {
        int u = (t >= off) ? s[t - off] : 0;
        __syncthreads();
        s[t] += u;
        __syncthreads();
    }
    if (t < nb) bsum[t] = s[t] - v;   // exclusive
}

// phase 3: per-block exclusive scan + block prefix; write offs, cursor, and
// the self-loop CSR entry (slot 0 of each node's segment, raw weight 1.0).
__global__ void scan_write_kernel(const int* __restrict__ cnt,
                                  const int* __restrict__ bsum,
                                  int* __restrict__ offs, int* __restrict__ cursor,
                                  int2* __restrict__ csr, int n) {
    __shared__ int s[SCAN_B];
    const int t = threadIdx.x;
    const int i = blockIdx.x * SCAN_B + t;
    const int v = (i < n) ? cnt[i] + 1 : 0;
    s[t] = v;
    __syncthreads();
    for (int off = 1; off < SCAN_B; off <<= 1) {
        int u = (t >= off) ? s[t - off] : 0;
        __syncthreads();
        s[t] += u;
        __syncthreads();
    }
    const int excl = s[t] - v + bsum[blockIdx.x];
    if (i < n) {
        offs[i] = excl;
        cursor[i] = excl + 1;               // slot 0 = self-loop, cursor past it
        csr[excl] = make_int2(i, __float_as_int(1.0f));
        if (i == n - 1) offs[n] = excl + v; // = n + e
    }
}

__global__ void fill_kernel(const int* __restrict__ row, const int* __restrict__ col,
                            const float* __restrict__ ew,
                            int* __restrict__ cursor, int2* __restrict__ csr, int E) {
    int e = blockIdx.x * blockDim.x + threadIdx.x;
    if (e < E) {
        int c = col[e];
        int pos = atomicAdd(&cursor[c], 1);
        csr[pos] = make_int2(row[e], __float_as_int(ew[e]));
    }
}

// ---------------- fp32 tiled GEMM: C[n][o] = dinv[n] * sum_k A[n][k] * W[o][k] ----------------

template <int BM, int BN>
__global__ void gemm_kernel(const float* __restrict__ A, const float* __restrict__ W,
                            const float* __restrict__ dinv,
                            float* __restrict__ C, int nrows) {
    constexpr int BK = 16;
    constexpr int TY = BM / 8;
    constexpr int TX = BN / 8;
    constexpr int NT = TY * TX;
    __shared__ float As[BK][BM + 4];
    __shared__ float Bs[BK][BN + 4];

    const int tid = threadIdx.x;
    const int tx = tid % TX;
    const int ty = tid / TX;
    const int row0 = blockIdx.x * BM;

    float acc[8][8] = {};

    for (int k0 = 0; k0 < K_DIM; k0 += BK) {
        constexpr int ITA = (BM * 4) / NT;
#pragma unroll
        for (int p = 0; p < ITA; ++p) {
            int lin = tid + p * NT;           // 0 .. BM*4-1
            int r = lin >> 2;
            int kq = lin & 3;
            int gr = row0 + r;
            if (gr > nrows - 1) gr = nrows - 1;
            const float4 v = *(const float4*)(A + (size_t)gr * K_DIM + k0 + kq * 4);
            As[kq * 4 + 0][r] = v.x;
            As[kq * 4 + 1][r] = v.y;
            As[kq * 4 + 2][r] = v.z;
            As[kq * 4 + 3][r] = v.w;
        }
        constexpr int ITB = (BN * 4) / NT;
#pragma unroll
        for (int p = 0; p < ITB; ++p) {
            int lin = tid + p * NT;
            int o = lin >> 2;
            int kq = lin & 3;
            const float4 v = *(const float4*)(W + (size_t)o * K_DIM + k0 + kq * 4);
            Bs[kq * 4 + 0][o] = v.x;
            Bs[kq * 4 + 1][o] = v.y;
            Bs[kq * 4 + 2][o] = v.z;
            Bs[kq * 4 + 3][o] = v.w;
        }
        __syncthreads();
#pragma unroll
        for (int kk = 0; kk < BK; ++kk) {
            float a[8], b[8];
#pragma unroll
            for (int i = 0; i < 8; ++i) a[i] = As[kk][ty * 8 + i];
#pragma unroll
            for (int j = 0; j < 8; ++j) b[j] = Bs[kk][tx * 8 + j];
#pragma unroll
            for (int i = 0; i < 8; ++i)
#pragma unroll
                for (int j = 0; j < 8; ++j)
                    acc[i][j] = fmaf(a[i], b[j], acc[i][j]);
        }
        __syncthreads();
    }

#pragma unroll
    for (int i = 0; i < 8; ++i) {
        int gr = row0 + ty * 8 + i;
        if (gr < nrows) {
            const float dv = dinv[gr];
#pragma unroll
            for (int j = 0; j < 8; j += 4) {
                float4 v = make_float4(acc[i][j] * dv, acc[i][j + 1] * dv,
                                       acc[i][j + 2] * dv, acc[i][j + 3] * dv);
                *(float4*)(C + (size_t)gr * BN + tx * 8 + j) = v;
            }
        }
    }
}

// ---------------- aggregation: out[i] = relu(bias + dinv[i] * sum_e w_e * m[src_e]) ----------------
// one wave per node; D=128: lane handles f and f+64; D=64: lane handles f.
// 4-edge unroll for memory-level parallelism (gather is L3-latency-bound).

template <int D>
__global__ __launch_bounds__(256) void agg_kernel(
    const float* __restrict__ m, const int* __restrict__ offs,
    const int2* __restrict__ csr, const float* __restrict__ dinv,
    const float* __restrict__ bias, float* __restrict__ out, int n) {
    const int wid = threadIdx.x >> 6;
    const int lane = threadIdx.x & 63;
    const int node = (blockIdx.x << 2) + wid;
    if (node >= n) return;
    const int beg = offs[node];
    const int end = offs[node + 1];
    float acc0 = 0.f, acc1 = 0.f;
    int k = beg;
    for (; k + 4 <= end; k += 4) {
        int2 e0 = csr[k], e1 = csr[k + 1], e2 = csr[k + 2], e3 = csr[k + 3];
        const float* r0 = m + (size_t)e0.x * D;
        const float* r1 = m + (size_t)e1.x * D;
        const float* r2 = m + (size_t)e2.x * D;
        const float* r3 = m + (size_t)e3.x * D;
        float w0 = __int_as_float(e0.y), w1 = __int_as_float(e1.y);
        float w2 = __int_as_float(e2.y), w3 = __int_as_float(e3.y);
        float v0 = r0[lane], v1 = r1[lane], v2 = r2[lane], v3 = r3[lane];
        acc0 = fmaf(w0, v0, acc0);
        acc0 = fmaf(w1, v1, acc0);
        acc0 = fmaf(w2, v2, acc0);
        acc0 = fmaf(w3, v3, acc0);
        if (D == 128) {
            float u0 = r0[lane + 64], u1 = r1[lane + 64];
            float u2 = r2[lane + 64], u3 = r3[lane + 64];
            acc1 = fmaf(w0, u0, acc1);
            acc1 = fmaf(w1, u1, acc1);
            acc1 = fmaf(w2, u2, acc1);
            acc1 = fmaf(w3, u3, acc1);
        }
    }
    for (; k < end; ++k) {
        int2 e0 = csr[k];
        float w0 = __int_as_float(e0.y);
        const float* r0 = m + (size_t)e0.x * D;
        acc0 = fmaf(w0, r0[lane], acc0);
        if (D == 128) acc1 = fmaf(w0, r0[lane + 64], acc1);
    }
    const float dv = dinv[node];
    float* orow = out + (size_t)node * D;
    orow[lane] = fmaxf(acc0 * dv + bias[lane], 0.f);
    if (D == 128) orow[lane + 64] = fmaxf(acc1 * dv + bias[lane + 64], 0.f);
}

// ---------------- launch ----------------

extern "C" void kernel_launch(void* const* d_in, const int* in_sizes, int n_in,
                              void* d_out, int out_size, void* d_ws, size_t ws_size,
                              hipStream_t stream) {
    const float* x  = (const float*)d_in[0];
    const int*   ei = (const int*)d_in[1];   // [2, E] int32
    const float* ew = (const float*)d_in[2];
    const float* W1 = (const float*)d_in[3];
    const float* b1 = (const float*)d_in[4];
    const float* W2 = (const float*)d_in[5];
    const float* b2 = (const float*)d_in[6];
    const float* W3 = (const float*)d_in[7];
    const float* b3 = (const float*)d_in[8];
    float* out = (float*)d_out;

    const int N = in_sizes[0] / K_DIM;      // 50000
    const int E = in_sizes[2];              // 800000
    const int* row = ei;                    // edge_index[0] (source)
    const int* col = ei + E;                // edge_index[1] (target / aggregation)

    const int nb = (N + SCAN_B - 1) / SCAN_B;   // scan blocks (196 <= 256)

    // workspace layout (~59 MB), 8B-aligned sections first
    unsigned long long* packed = (unsigned long long*)d_ws;    // N u64
    float* m_buf  = (float*)(packed + N);                      // N*128
    float* h_buf  = m_buf + (size_t)N * K_DIM;                 // N*128
    int2*  csr    = (int2*)(h_buf + (size_t)N * K_DIM);        // N+E int2
    int*   offs   = (int*)(csr + (size_t)(N + E));             // N+1
    int*   cursor = offs + (N + 1);                            // N
    float* dinv   = (float*)(cursor + N);                      // N
    int*   cnt    = (int*)(dinv + N);                          // N
    int*   bsum   = cnt + N;                                   // nb

    hipMemsetAsync(packed, 0, (size_t)N * sizeof(unsigned long long), stream);

    degree_kernel<<<(E + 255) / 256, 256, 0, stream>>>(col, ew, packed, E);
    dinv_kernel<<<(N + 255) / 256, 256, 0, stream>>>(packed, dinv, cnt, N);
    block_reduce_kernel<<<nb, SCAN_B, 0, stream>>>(cnt, bsum, N);
    bsum_scan_kernel<<<1, SCAN_B, 0, stream>>>(bsum, nb);
    scan_write_kernel<<<nb, SCAN_B, 0, stream>>>(cnt, bsum, offs, cursor, csr, N);
    fill_kernel<<<(E + 255) / 256, 256, 0, stream>>>(row, col, ew, cursor, csr, E);

    const int gemm_blocks = (N + 63) / 64;
    const int agg_blocks = (N + 3) / 4;

    // layer 1: m = dinv * (x @ W1^T) ; h = relu(dinv * agg(m) + b1)
    gemm_kernel<64, 128><<<gemm_blocks, 128, 0, stream>>>(x, W1, dinv, m_buf, N);
    agg_kernel<128><<<agg_blocks, 256, 0, stream>>>(m_buf, offs, csr, dinv, b1, h_buf, N);
    // layer 2
    gemm_kernel<64, 128><<<gemm_blocks, 128, 0, stream>>>(h_buf, W2, dinv, m_buf, N);
    agg_kernel<128><<<agg_blocks, 256, 0, stream>>>(m_buf, offs, csr, dinv, b2, h_buf, N);
    // layer 3: F_OUT=64, write d_out directly
    gemm_kernel<64, 64><<<gemm_blocks, 64, 0, stream>>>(h_buf, W3, dinv, m_buf, N);
    agg_kernel<64><<<agg_blocks, 256, 0, stream>>>(m_buf, offs, csr, dinv, b3, out, N);
}

// Round 4
// 410.596 us; speedup vs baseline: 1.7600x; 1.0986x over previous
//
#include <hip/hip_runtime.h>
#include <hip/hip_fp16.h>

// GraphEmbedNet: 3-layer GCN, N=50000, E=800000, F=128/128/64.
// R3: agg gather is BW-bound (188 MB HBM fetch/layer vs 25.6 MB buffer --
// random gather misses the 4MB/XCD L2). Fix: message buffer m in fp16 ->
// half the gather bytes; one __half2 dword per lane per row. Accumulate fp32.

#define K_DIM 128
#define SCAN_B 256        // elements per scan block
#define FIXP 1048576.0f   // 2^20 fixed-point scale for weighted degree

// ---------------- CSR build ----------------

// one u64 atomic per edge: bits [40..) = count, [0..40) = sum(ew) * 2^20
__global__ void degree_kernel(const int* __restrict__ col, const float* __restrict__ ew,
                              unsigned long long* __restrict__ packed, int E) {
    int e = blockIdx.x * blockDim.x + threadIdx.x;
    if (e < E) {
        int c = col[e];
        unsigned long long add = (1ULL << 40) +
            (unsigned long long)(ew[e] * FIXP + 0.5f);
        atomicAdd(&packed[c], add);
    }
}

// unpack: dinv[i] = rsqrt(degw + 1), cnt[i] = count
__global__ void dinv_kernel(const unsigned long long* __restrict__ packed,
                            float* __restrict__ dinv, int* __restrict__ cnt, int n) {
    int i = blockIdx.x * blockDim.x + threadIdx.x;
    if (i < n) {
        unsigned long long p = packed[i];
        float degw = (float)(p & 0xFFFFFFFFFFULL) * (1.0f / FIXP);
        dinv[i] = rsqrtf(degw + 1.0f);
        cnt[i] = (int)(p >> 40);
    }
}

// phase 1: per-block sum of (cnt[i]+1)
__global__ void block_reduce_kernel(const int* __restrict__ cnt, int* __restrict__ bsum, int n) {
    __shared__ int s[SCAN_B];
    const int t = threadIdx.x;
    const int i = blockIdx.x * SCAN_B + t;
    s[t] = (i < n) ? cnt[i] + 1 : 0;
    __syncthreads();
    for (int off = SCAN_B / 2; off > 0; off >>= 1) {
        if (t < off) s[t] += s[t + off];
        __syncthreads();
    }
    if (t == 0) bsum[blockIdx.x] = s[0];
}

// phase 2: single block, exclusive scan of nb (<=256) block sums in place
__global__ void bsum_scan_kernel(int* __restrict__ bsum, int nb) {
    __shared__ int s[SCAN_B];
    const int t = threadIdx.x;
    const int v = (t < nb) ? bsum[t] : 0;
    s[t] = v;
    __syncthreads();
    for (int off = 1; off < SCAN_B; off <<= 1) {
        int u = (t >= off) ? s[t - off] : 0;
        __syncthreads();
        s[t] += u;
        __syncthreads();
    }
    if (t < nb) bsum[t] = s[t] - v;   // exclusive
}

// phase 3: per-block exclusive scan + block prefix; write offs, cursor, and
// the self-loop CSR entry (slot 0 of each node's segment, raw weight 1.0).
__global__ void scan_write_kernel(const int* __restrict__ cnt,
                                  const int* __restrict__ bsum,
                                  int* __restrict__ offs, int* __restrict__ cursor,
                                  int2* __restrict__ csr, int n) {
    __shared__ int s[SCAN_B];
    const int t = threadIdx.x;
    const int i = blockIdx.x * SCAN_B + t;
    const int v = (i < n) ? cnt[i] + 1 : 0;
    s[t] = v;
    __syncthreads();
    for (int off = 1; off < SCAN_B; off <<= 1) {
        int u = (t >= off) ? s[t - off] : 0;
        __syncthreads();
        s[t] += u;
        __syncthreads();
    }
    const int excl = s[t] - v + bsum[blockIdx.x];
    if (i < n) {
        offs[i] = excl;
        cursor[i] = excl + 1;               // slot 0 = self-loop, cursor past it
        csr[excl] = make_int2(i, __float_as_int(1.0f));
        if (i == n - 1) offs[n] = excl + v; // = n + e
    }
}

__global__ void fill_kernel(const int* __restrict__ row, const int* __restrict__ col,
                            const float* __restrict__ ew,
                            int* __restrict__ cursor, int2* __restrict__ csr, int E) {
    int e = blockIdx.x * blockDim.x + threadIdx.x;
    if (e < E) {
        int c = col[e];
        int pos = atomicAdd(&cursor[c], 1);
        csr[pos] = make_int2(row[e], __float_as_int(ew[e]));
    }
}

// ---------------- fp32 tiled GEMM, fp16 output: C[n][o] = half(dinv[n] * sum_k A[n][k] * W[o][k]) ----------------

template <int BM, int BN>
__global__ void gemm_kernel(const float* __restrict__ A, const float* __restrict__ W,
                            const float* __restrict__ dinv,
                            __half* __restrict__ C, int nrows) {
    constexpr int BK = 16;
    constexpr int TY = BM / 8;
    constexpr int TX = BN / 8;
    constexpr int NT = TY * TX;
    __shared__ float As[BK][BM + 4];
    __shared__ float Bs[BK][BN + 4];

    const int tid = threadIdx.x;
    const int tx = tid % TX;
    const int ty = tid / TX;
    const int row0 = blockIdx.x * BM;

    float acc[8][8] = {};

    for (int k0 = 0; k0 < K_DIM; k0 += BK) {
        constexpr int ITA = (BM * 4) / NT;
#pragma unroll
        for (int p = 0; p < ITA; ++p) {
            int lin = tid + p * NT;           // 0 .. BM*4-1
            int r = lin >> 2;
            int kq = lin & 3;
            int gr = row0 + r;
            if (gr > nrows - 1) gr = nrows - 1;
            const float4 v = *(const float4*)(A + (size_t)gr * K_DIM + k0 + kq * 4);
            As[kq * 4 + 0][r] = v.x;
            As[kq * 4 + 1][r] = v.y;
            As[kq * 4 + 2][r] = v.z;
            As[kq * 4 + 3][r] = v.w;
        }
        constexpr int ITB = (BN * 4) / NT;
#pragma unroll
        for (int p = 0; p < ITB; ++p) {
            int lin = tid + p * NT;
            int o = lin >> 2;
            int kq = lin & 3;
            const float4 v = *(const float4*)(W + (size_t)o * K_DIM + k0 + kq * 4);
            Bs[kq * 4 + 0][o] = v.x;
            Bs[kq * 4 + 1][o] = v.y;
            Bs[kq * 4 + 2][o] = v.z;
            Bs[kq * 4 + 3][o] = v.w;
        }
        __syncthreads();
#pragma unroll
        for (int kk = 0; kk < BK; ++kk) {
            float a[8], b[8];
#pragma unroll
            for (int i = 0; i < 8; ++i) a[i] = As[kk][ty * 8 + i];
#pragma unroll
            for (int j = 0; j < 8; ++j) b[j] = Bs[kk][tx * 8 + j];
#pragma unroll
            for (int i = 0; i < 8; ++i)
#pragma unroll
                for (int j = 0; j < 8; ++j)
                    acc[i][j] = fmaf(a[i], b[j], acc[i][j]);
        }
        __syncthreads();
    }

#pragma unroll
    for (int i = 0; i < 8; ++i) {
        int gr = row0 + ty * 8 + i;
        if (gr < nrows) {
            const float dv = dinv[gr];
#pragma unroll
            for (int j = 0; j < 8; j += 4) {
                __half2 h01 = __floats2half2_rn(acc[i][j] * dv, acc[i][j + 1] * dv);
                __half2 h23 = __floats2half2_rn(acc[i][j + 2] * dv, acc[i][j + 3] * dv);
                __half2 pair[2] = {h01, h23};
                *(float2*)(C + (size_t)gr * BN + tx * 8 + j) = *(float2*)pair;
            }
        }
    }
}

// ---------------- aggregation: out[i] = relu(bias + dinv[i] * sum_e w_e * m[src_e]) ----------------
// m is fp16. D=128: one wave per node, lane handles features (2l, 2l+1) via one
// __half2 load per row. D=64: half-wave per edge parity, shfl_xor(32) combine.

template <int D>
__global__ __launch_bounds__(256) void agg_kernel(
    const __half* __restrict__ m, const int* __restrict__ offs,
    const int2* __restrict__ csr, const float* __restrict__ dinv,
    const float* __restrict__ bias, float* __restrict__ out, int n) {
    const int wid = threadIdx.x >> 6;
    const int lane = threadIdx.x & 63;
    const int node = (blockIdx.x << 2) + wid;
    if (node >= n) return;
    const int beg = offs[node];
    const int end = offs[node + 1];
    const __half2* mh = (const __half2*)m;   // row stride D/2 half2
    float acc0 = 0.f, acc1 = 0.f;

    if constexpr (D == 128) {
        int k = beg;
        for (; k + 4 <= end; k += 4) {
            int2 e0 = csr[k], e1 = csr[k + 1], e2 = csr[k + 2], e3 = csr[k + 3];
            float2 f0 = __half22float2(mh[(size_t)e0.x * 64 + lane]);
            float2 f1 = __half22float2(mh[(size_t)e1.x * 64 + lane]);
            float2 f2 = __half22float2(mh[(size_t)e2.x * 64 + lane]);
            float2 f3 = __half22float2(mh[(size_t)e3.x * 64 + lane]);
            float w0 = __int_as_float(e0.y), w1 = __int_as_float(e1.y);
            float w2 = __int_as_float(e2.y), w3 = __int_as_float(e3.y);
            acc0 = fmaf(w0, f0.x, acc0); acc1 = fmaf(w0, f0.y, acc1);
            acc0 = fmaf(w1, f1.x, acc0); acc1 = fmaf(w1, f1.y, acc1);
            acc0 = fmaf(w2, f2.x, acc0); acc1 = fmaf(w2, f2.y, acc1);
            acc0 = fmaf(w3, f3.x, acc0); acc1 = fmaf(w3, f3.y, acc1);
        }
        for (; k < end; ++k) {
            int2 e0 = csr[k];
            float w0 = __int_as_float(e0.y);
            float2 f0 = __half22float2(mh[(size_t)e0.x * 64 + lane]);
            acc0 = fmaf(w0, f0.x, acc0); acc1 = fmaf(w0, f0.y, acc1);
        }
        const float dv = dinv[node];
        const float2 bv = *(const float2*)(bias + 2 * lane);
        float2 o;
        o.x = fmaxf(acc0 * dv + bv.x, 0.f);
        o.y = fmaxf(acc1 * dv + bv.y, 0.f);
        *(float2*)(out + (size_t)node * 128 + 2 * lane) = o;
    } else {
        // D == 64: lanes 0-31 take even edges, 32-63 odd; feature pair (2sl, 2sl+1)
        const int half = lane >> 5;
        const int sl = lane & 31;
        int k = beg;
        for (; k + 8 <= end; k += 8) {
            int2 e0 = csr[k + half], e1 = csr[k + 2 + half];
            int2 e2 = csr[k + 4 + half], e3 = csr[k + 6 + half];
            float2 f0 = __half22float2(mh[(size_t)e0.x * 32 + sl]);
            float2 f1 = __half22float2(mh[(size_t)e1.x * 32 + sl]);
            float2 f2 = __half22float2(mh[(size_t)e2.x * 32 + sl]);
            float2 f3 = __half22float2(mh[(size_t)e3.x * 32 + sl]);
            float w0 = __int_as_float(e0.y), w1 = __int_as_float(e1.y);
            float w2 = __int_as_float(e2.y), w3 = __int_as_float(e3.y);
            acc0 = fmaf(w0, f0.x, acc0); acc1 = fmaf(w0, f0.y, acc1);
            acc0 = fmaf(w1, f1.x, acc0); acc1 = fmaf(w1, f1.y, acc1);
            acc0 = fmaf(w2, f2.x, acc0); acc1 = fmaf(w2, f2.y, acc1);
            acc0 = fmaf(w3, f3.x, acc0); acc1 = fmaf(w3, f3.y, acc1);
        }
        for (; k + 2 <= end; k += 2) {
            int2 e0 = csr[k + half];
            float w0 = __int_as_float(e0.y);
            float2 f0 = __half22float2(mh[(size_t)e0.x * 32 + sl]);
            acc0 = fmaf(w0, f0.x, acc0); acc1 = fmaf(w0, f0.y, acc1);
        }
        if (k < end && half == 0) {
            int2 e0 = csr[k];
            float w0 = __int_as_float(e0.y);
            float2 f0 = __half22float2(mh[(size_t)e0.x * 32 + sl]);
            acc0 = fmaf(w0, f0.x, acc0); acc1 = fmaf(w0, f0.y, acc1);
        }
        acc0 += __shfl_xor(acc0, 32);
        acc1 += __shfl_xor(acc1, 32);
        if (half == 0) {
            const float dv = dinv[node];
            const float2 bv = *(const float2*)(bias + 2 * sl);
            float2 o;
            o.x = fmaxf(acc0 * dv + bv.x, 0.f);
            o.y = fmaxf(acc1 * dv + bv.y, 0.f);
            *(float2*)(out + (size_t)node * 64 + 2 * sl) = o;
        }
    }
}

// ---------------- launch ----------------

extern "C" void kernel_launch(void* const* d_in, const int* in_sizes, int n_in,
                              void* d_out, int out_size, void* d_ws, size_t ws_size,
                              hipStream_t stream) {
    const float* x  = (const float*)d_in[0];
    const int*   ei = (const int*)d_in[1];   // [2, E] int32
    const float* ew = (const float*)d_in[2];
    const float* W1 = (const float*)d_in[3];
    const float* b1 = (const float*)d_in[4];
    const float* W2 = (const float*)d_in[5];
    const float* b2 = (const float*)d_in[6];
    const float* W3 = (const float*)d_in[7];
    const float* b3 = (const float*)d_in[8];
    float* out = (float*)d_out;

    const int N = in_sizes[0] / K_DIM;      // 50000
    const int E = in_sizes[2];              // 800000
    const int* row = ei;                    // edge_index[0] (source)
    const int* col = ei + E;                // edge_index[1] (target / aggregation)

    const int nb = (N + SCAN_B - 1) / SCAN_B;   // scan blocks (196 <= 256)

    // workspace layout (~46 MB), 8B-aligned sections first
    unsigned long long* packed = (unsigned long long*)d_ws;    // N u64
    __half* m_buf = (__half*)(packed + N);                     // N*128 fp16
    float* h_buf  = (float*)(m_buf + (size_t)N * K_DIM);       // N*128 fp32
    int2*  csr    = (int2*)(h_buf + (size_t)N * K_DIM);        // N+E int2
    int*   offs   = (int*)(csr + (size_t)(N + E));             // N+1
    int*   cursor = offs + (N + 1);                            // N
    float* dinv   = (float*)(cursor + N);                      // N
    int*   cnt    = (int*)(dinv + N);                          // N
    int*   bsum   = cnt + N;                                   // nb

    hipMemsetAsync(packed, 0, (size_t)N * sizeof(unsigned long long), stream);

    degree_kernel<<<(E + 255) / 256, 256, 0, stream>>>(col, ew, packed, E);
    dinv_kernel<<<(N + 255) / 256, 256, 0, stream>>>(packed, dinv, cnt, N);
    block_reduce_kernel<<<nb, SCAN_B, 0, stream>>>(cnt, bsum, N);
    bsum_scan_kernel<<<1, SCAN_B, 0, stream>>>(bsum, nb);
    scan_write_kernel<<<nb, SCAN_B, 0, stream>>>(cnt, bsum, offs, cursor, csr, N);
    fill_kernel<<<(E + 255) / 256, 256, 0, stream>>>(row, col, ew, cursor, csr, E);

    const int gemm_blocks = (N + 63) / 64;
    const int agg_blocks = (N + 3) / 4;

    // layer 1: m = fp16(dinv * (x @ W1^T)) ; h = relu(dinv * agg(m) + b1)
    gemm_kernel<64, 128><<<gemm_blocks, 128, 0, stream>>>(x, W1, dinv, m_buf, N);
    agg_kernel<128><<<agg_blocks, 256, 0, stream>>>(m_buf, offs, csr, dinv, b1, h_buf, N);
    // layer 2
    gemm_kernel<64, 128><<<gemm_blocks, 128, 0, stream>>>(h_buf, W2, dinv, m_buf, N);
    agg_kernel<128><<<agg_blocks, 256, 0, stream>>>(m_buf, offs, csr, dinv, b2, h_buf, N);
    // layer 3: F_OUT=64, write d_out directly
    gemm_kernel<64, 64><<<gemm_blocks, 64, 0, stream>>>(h_buf, W3, dinv, m_buf, N);
    agg_kernel<64><<<agg_blocks, 256, 0, stream>>>(m_buf, offs, csr, dinv, b3, out, N);
}

// Round 5
// 359.840 us; speedup vs baseline: 2.0083x; 1.1411x over previous
//
#include <hip/hip_runtime.h>
#include <hip/hip_fp16.h>

// GraphEmbedNet: 3-layer GCN, N=50000, E=800000, F=128/128/64.
// R4: GEMMs moved to fp16 MFMA (16x16x32_f16, fp32 accum), h stored fp16.
// Fragment layouts per verified guide: A[m=lane&15][k=quad*8+j],
// B[n=lane&15][k=quad*8+j], C/D col=lane&15 row=quad*4+reg.

#define K_DIM 128
#define SCAN_B 256        // elements per scan block
#define FIXP 1048576.0f   // 2^20 fixed-point scale for weighted degree

using half8  = __attribute__((ext_vector_type(8))) _Float16;
using floatx4 = __attribute__((ext_vector_type(4))) float;

// ---------------- CSR build ----------------

// one u64 atomic per edge: bits [40..) = count, [0..40) = sum(ew) * 2^20
__global__ void degree_kernel(const int* __restrict__ col, const float* __restrict__ ew,
                              unsigned long long* __restrict__ packed, int E) {
    int e = blockIdx.x * blockDim.x + threadIdx.x;
    if (e < E) {
        int c = col[e];
        unsigned long long add = (1ULL << 40) +
            (unsigned long long)(ew[e] * FIXP + 0.5f);
        atomicAdd(&packed[c], add);
    }
}

// unpack: dinv[i] = rsqrt(degw + 1), cnt[i] = count
__global__ void dinv_kernel(const unsigned long long* __restrict__ packed,
                            float* __restrict__ dinv, int* __restrict__ cnt, int n) {
    int i = blockIdx.x * blockDim.x + threadIdx.x;
    if (i < n) {
        unsigned long long p = packed[i];
        float degw = (float)(p & 0xFFFFFFFFFFULL) * (1.0f / FIXP);
        dinv[i] = rsqrtf(degw + 1.0f);
        cnt[i] = (int)(p >> 40);
    }
}

// phase 1: per-block sum of (cnt[i]+1)
__global__ void block_reduce_kernel(const int* __restrict__ cnt, int* __restrict__ bsum, int n) {
    __shared__ int s[SCAN_B];
    const int t = threadIdx.x;
    const int i = blockIdx.x * SCAN_B + t;
    s[t] = (i < n) ? cnt[i] + 1 : 0;
    __syncthreads();
    for (int off = SCAN_B / 2; off > 0; off >>= 1) {
        if (t < off) s[t] += s[t + off];
        __syncthreads();
    }
    if (t == 0) bsum[blockIdx.x] = s[0];
}

// phase 2: single block, exclusive scan of nb (<=256) block sums in place
__global__ void bsum_scan_kernel(int* __restrict__ bsum, int nb) {
    __shared__ int s[SCAN_B];
    const int t = threadIdx.x;
    const int v = (t < nb) ? bsum[t] : 0;
    s[t] = v;
    __syncthreads();
    for (int off = 1; off < SCAN_B; off <<= 1) {
        int u = (t >= off) ? s[t - off] : 0;
        __syncthreads();
        s[t] += u;
        __syncthreads();
    }
    if (t < nb) bsum[t] = s[t] - v;   // exclusive
}

// phase 3: per-block exclusive scan + block prefix; write offs, cursor, and
// the self-loop CSR entry (slot 0 of each node's segment, raw weight 1.0).
__global__ void scan_write_kernel(const int* __restrict__ cnt,
                                  const int* __restrict__ bsum,
                                  int* __restrict__ offs, int* __restrict__ cursor,
                                  int2* __restrict__ csr, int n) {
    __shared__ int s[SCAN_B];
    const int t = threadIdx.x;
    const int i = blockIdx.x * SCAN_B + t;
    const int v = (i < n) ? cnt[i] + 1 : 0;
    s[t] = v;
    __syncthreads();
    for (int off = 1; off < SCAN_B; off <<= 1) {
        int u = (t >= off) ? s[t - off] : 0;
        __syncthreads();
        s[t] += u;
        __syncthreads();
    }
    const int excl = s[t] - v + bsum[blockIdx.x];
    if (i < n) {
        offs[i] = excl;
        cursor[i] = excl + 1;               // slot 0 = self-loop, cursor past it
        csr[excl] = make_int2(i, __float_as_int(1.0f));
        if (i == n - 1) offs[n] = excl + v; // = n + e
    }
}

__global__ void fill_kernel(const int* __restrict__ row, const int* __restrict__ col,
                            const float* __restrict__ ew,
                            int* __restrict__ cursor, int2* __restrict__ csr, int E) {
    int e = blockIdx.x * blockDim.x + threadIdx.x;
    if (e < E) {
        int c = col[e];
        int pos = atomicAdd(&cursor[c], 1);
        csr[pos] = make_int2(row[e], __float_as_int(ew[e]));
    }
}

// convert W1|W2|W3 (fp32) -> contiguous fp16 buffer
__global__ void w2h_kernel(const float* __restrict__ W1, const float* __restrict__ W2,
                           const float* __restrict__ W3, __half* __restrict__ Wh,
                           int n1, int n2, int n3) {
    int i = blockIdx.x * blockDim.x + threadIdx.x;
    if (i >= n1 + n2 + n3) return;
    float v = (i < n1) ? W1[i] : (i < n1 + n2 ? W2[i - n1] : W3[i - n1 - n2]);
    Wh[i] = __float2half_rn(v);
}

// ---------------- MFMA GEMM: C[n][o] = half(dinv[n] * sum_k A[n][k] * W[o][k]) ----------------
// A: [nrows,128] (fp32 if FP32IN else fp16); Wh: [BN,128] fp16; C: [nrows,BN] fp16.
// 256 threads = 4 waves; wave handles 16 rows x BN cols; K=128 in 4 chunks of 32.

template <int BN, bool FP32IN>
__global__ __launch_bounds__(256) void mfma_gemm(const void* __restrict__ Ain,
                                                 const __half* __restrict__ Wh,
                                                 const float* __restrict__ dinv,
                                                 __half* __restrict__ C, int nrows) {
    constexpr int NT = BN / 16;
    const int wave = threadIdx.x >> 6;
    const int lane = threadIdx.x & 63;
    const int quad = lane >> 4;
    const int l16  = lane & 15;
    const int row0 = blockIdx.x * 64 + wave * 16;

    int arow = row0 + l16;
    if (arow > nrows - 1) arow = nrows - 1;

    floatx4 acc[NT] = {};

#pragma unroll
    for (int kc = 0; kc < 4; ++kc) {
        const int kof = kc * 32 + quad * 8;
        half8 af;
        if constexpr (FP32IN) {
            const float* ap = (const float*)Ain + (size_t)arow * K_DIM + kof;
            float4 f0 = *(const float4*)ap;
            float4 f1 = *(const float4*)(ap + 4);
            af[0] = (_Float16)f0.x; af[1] = (_Float16)f0.y;
            af[2] = (_Float16)f0.z; af[3] = (_Float16)f0.w;
            af[4] = (_Float16)f1.x; af[5] = (_Float16)f1.y;
            af[6] = (_Float16)f1.z; af[7] = (_Float16)f1.w;
        } else {
            af = *(const half8*)((const __half*)Ain + (size_t)arow * K_DIM + kof);
        }
#pragma unroll
        for (int ct = 0; ct < NT; ++ct) {
            half8 bf = *(const half8*)(Wh + (size_t)(ct * 16 + l16) * K_DIM + kof);
            acc[ct] = __builtin_amdgcn_mfma_f32_16x16x32_f16(af, bf, acc[ct], 0, 0, 0);
        }
    }

    // epilogue: D(row=quad*4+r, col=ct*16+l16)
    float dv[4];
    int grow[4];
    bool ok[4];
#pragma unroll
    for (int r = 0; r < 4; ++r) {
        grow[r] = row0 + quad * 4 + r;
        ok[r] = grow[r] < nrows;
        dv[r] = ok[r] ? dinv[grow[r]] : 0.f;
    }
#pragma unroll
    for (int ct = 0; ct < NT; ++ct) {
        const int colb = ct * 16 + l16;
#pragma unroll
        for (int r = 0; r < 4; ++r)
            if (ok[r])
                C[(size_t)grow[r] * BN + colb] = __float2half_rn(acc[ct][r] * dv[r]);
    }
}

// ---------------- aggregation: out[i] = relu(bias + dinv[i] * sum_e w_e * m[src_e]) ----------------
// m is fp16. D=128: one wave per node, lane handles features (2l, 2l+1).
// D=64: half-wave per edge parity, shfl_xor(32) combine. OUT half or float.

template <int D, typename OUT>
__global__ __launch_bounds__(256) void agg_kernel(
    const __half* __restrict__ m, const int* __restrict__ offs,
    const int2* __restrict__ csr, const float* __restrict__ dinv,
    const float* __restrict__ bias, OUT* __restrict__ out, int n) {
    const int wid = threadIdx.x >> 6;
    const int lane = threadIdx.x & 63;
    const int node = (blockIdx.x << 2) + wid;
    if (node >= n) return;
    const int beg = offs[node];
    const int end = offs[node + 1];
    const __half2* mh = (const __half2*)m;   // row stride D/2 half2
    float acc0 = 0.f, acc1 = 0.f;

    if constexpr (D == 128) {
        int k = beg;
        for (; k + 4 <= end; k += 4) {
            int2 e0 = csr[k], e1 = csr[k + 1], e2 = csr[k + 2], e3 = csr[k + 3];
            float2 f0 = __half22float2(mh[(size_t)e0.x * 64 + lane]);
            float2 f1 = __half22float2(mh[(size_t)e1.x * 64 + lane]);
            float2 f2 = __half22float2(mh[(size_t)e2.x * 64 + lane]);
            float2 f3 = __half22float2(mh[(size_t)e3.x * 64 + lane]);
            float w0 = __int_as_float(e0.y), w1 = __int_as_float(e1.y);
            float w2 = __int_as_float(e2.y), w3 = __int_as_float(e3.y);
            acc0 = fmaf(w0, f0.x, acc0); acc1 = fmaf(w0, f0.y, acc1);
            acc0 = fmaf(w1, f1.x, acc0); acc1 = fmaf(w1, f1.y, acc1);
            acc0 = fmaf(w2, f2.x, acc0); acc1 = fmaf(w2, f2.y, acc1);
            acc0 = fmaf(w3, f3.x, acc0); acc1 = fmaf(w3, f3.y, acc1);
        }
        for (; k < end; ++k) {
            int2 e0 = csr[k];
            float w0 = __int_as_float(e0.y);
            float2 f0 = __half22float2(mh[(size_t)e0.x * 64 + lane]);
            acc0 = fmaf(w0, f0.x, acc0); acc1 = fmaf(w0, f0.y, acc1);
        }
        const float dv = dinv[node];
        const float2 bv = *(const float2*)(bias + 2 * lane);
        float ox = fmaxf(acc0 * dv + bv.x, 0.f);
        float oy = fmaxf(acc1 * dv + bv.y, 0.f);
        if constexpr (sizeof(OUT) == 2) {
            ((__half2*)out)[(size_t)node * 64 + lane] = __floats2half2_rn(ox, oy);
        } else {
            *(float2*)((float*)out + (size_t)node * 128 + 2 * lane) = make_float2(ox, oy);
        }
    } else {
        // D == 64: lanes 0-31 take even edges, 32-63 odd; feature pair (2sl, 2sl+1)
        const int half = lane >> 5;
        const int sl = lane & 31;
        int k = beg;
        for (; k + 8 <= end; k += 8) {
            int2 e0 = csr[k + half], e1 = csr[k + 2 + half];
            int2 e2 = csr[k + 4 + half], e3 = csr[k + 6 + half];
            float2 f0 = __half22float2(mh[(size_t)e0.x * 32 + sl]);
            float2 f1 = __half22float2(mh[(size_t)e1.x * 32 + sl]);
            float2 f2 = __half22float2(mh[(size_t)e2.x * 32 + sl]);
            float2 f3 = __half22float2(mh[(size_t)e3.x * 32 + sl]);
            float w0 = __int_as_float(e0.y), w1 = __int_as_float(e1.y);
            float w2 = __int_as_float(e2.y), w3 = __int_as_float(e3.y);
            acc0 = fmaf(w0, f0.x, acc0); acc1 = fmaf(w0, f0.y, acc1);
            acc0 = fmaf(w1, f1.x, acc0); acc1 = fmaf(w1, f1.y, acc1);
            acc0 = fmaf(w2, f2.x, acc0); acc1 = fmaf(w2, f2.y, acc1);
            acc0 = fmaf(w3, f3.x, acc0); acc1 = fmaf(w3, f3.y, acc1);
        }
        for (; k + 2 <= end; k += 2) {
            int2 e0 = csr[k + half];
            float w0 = __int_as_float(e0.y);
            float2 f0 = __half22float2(mh[(size_t)e0.x * 32 + sl]);
            acc0 = fmaf(w0, f0.x, acc0); acc1 = fmaf(w0, f0.y, acc1);
        }
        if (k < end && half == 0) {
            int2 e0 = csr[k];
            float w0 = __int_as_float(e0.y);
            float2 f0 = __half22float2(mh[(size_t)e0.x * 32 + sl]);
            acc0 = fmaf(w0, f0.x, acc0); acc1 = fmaf(w0, f0.y, acc1);
        }
        acc0 += __shfl_xor(acc0, 32);
        acc1 += __shfl_xor(acc1, 32);
        if (half == 0) {
            const float dv = dinv[node];
            const float2 bv = *(const float2*)(bias + 2 * sl);
            float ox = fmaxf(acc0 * dv + bv.x, 0.f);
            float oy = fmaxf(acc1 * dv + bv.y, 0.f);
            *(float2*)((float*)out + (size_t)node * 64 + 2 * sl) = make_float2(ox, oy);
        }
    }
}

// ---------------- launch ----------------

extern "C" void kernel_launch(void* const* d_in, const int* in_sizes, int n_in,
                              void* d_out, int out_size, void* d_ws, size_t ws_size,
                              hipStream_t stream) {
    const float* x  = (const float*)d_in[0];
    const int*   ei = (const int*)d_in[1];   // [2, E] int32
    const float* ew = (const float*)d_in[2];
    const float* W1 = (const float*)d_in[3];
    const float* b1 = (const float*)d_in[4];
    const float* W2 = (const float*)d_in[5];
    const float* b2 = (const float*)d_in[6];
    const float* W3 = (const float*)d_in[7];
    const float* b3 = (const float*)d_in[8];
    float* out = (float*)d_out;

    const int N = in_sizes[0] / K_DIM;      // 50000
    const int E = in_sizes[2];              // 800000
    const int* row = ei;                    // edge_index[0] (source)
    const int* col = ei + E;                // edge_index[1] (target / aggregation)

    const int nb = (N + SCAN_B - 1) / SCAN_B;   // scan blocks (196 <= 256)
    const int NW1 = 128 * 128, NW2 = 128 * 128, NW3 = 64 * 128;

    // workspace layout, 8B-aligned sections first
    unsigned long long* packed = (unsigned long long*)d_ws;    // N u64
    __half* m_buf = (__half*)(packed + N);                     // N*128 fp16
    __half* h_buf = m_buf + (size_t)N * K_DIM;                 // N*128 fp16
    __half* Wh    = h_buf + (size_t)N * K_DIM;                 // 40960 fp16
    int2*  csr    = (int2*)(Wh + NW1 + NW2 + NW3);             // N+E int2
    int*   offs   = (int*)(csr + (size_t)(N + E));             // N+1
    int*   cursor = offs + (N + 1);                            // N
    float* dinv   = (float*)(cursor + N);                      // N
    int*   cnt    = (int*)(dinv + N);                          // N
    int*   bsum   = cnt + N;                                   // nb

    hipMemsetAsync(packed, 0, (size_t)N * sizeof(unsigned long long), stream);

    degree_kernel<<<(E + 255) / 256, 256, 0, stream>>>(col, ew, packed, E);
    dinv_kernel<<<(N + 255) / 256, 256, 0, stream>>>(packed, dinv, cnt, N);
    block_reduce_kernel<<<nb, SCAN_B, 0, stream>>>(cnt, bsum, N);
    bsum_scan_kernel<<<1, SCAN_B, 0, stream>>>(bsum, nb);
    scan_write_kernel<<<nb, SCAN_B, 0, stream>>>(cnt, bsum, offs, cursor, csr, N);
    fill_kernel<<<(E + 255) / 256, 256, 0, stream>>>(row, col, ew, cursor, csr, E);
    w2h_kernel<<<(NW1 + NW2 + NW3 + 255) / 256, 256, 0, stream>>>(W1, W2, W3, Wh,
                                                                  NW1, NW2, NW3);

    const int gemm_blocks = (N + 63) / 64;
    const int agg_blocks = (N + 3) / 4;

    // layer 1: m = fp16(dinv * (x @ W1^T)) ; h = fp16(relu(dinv * agg(m) + b1))
    mfma_gemm<128, true><<<gemm_blocks, 256, 0, stream>>>(x, Wh, dinv, m_buf, N);
    agg_kernel<128, __half><<<agg_blocks, 256, 0, stream>>>(m_buf, offs, csr, dinv, b1, h_buf, N);
    // layer 2
    mfma_gemm<128, false><<<gemm_blocks, 256, 0, stream>>>(h_buf, Wh + NW1, dinv, m_buf, N);
    agg_kernel<128, __half><<<agg_blocks, 256, 0, stream>>>(m_buf, offs, csr, dinv, b2, h_buf, N);
    // layer 3: F_OUT=64, write d_out (fp32) directly
    mfma_gemm<64, false><<<gemm_blocks, 256, 0, stream>>>(h_buf, Wh + NW1 + NW2, dinv, m_buf, N);
    agg_kernel<64, float><<<agg_blocks, 256, 0, stream>>>(m_buf, offs, csr, dinv, b3, out, N);
}

// Round 7
// 325.677 us; speedup vs baseline: 2.2190x; 1.1049x over previous
//
#include <hip/hip_runtime.h>
#include <hip/hip_fp16.h>

// GraphEmbedNet: 3-layer GCN, N=50000, E=800000, F=128/128/64.
// R6 (bisection): R5's chunked agg reverted to R4's known-good joint-edge agg;
// rank-trick atomic-free fill KEPT (semantically identical to R4's passing
// atomic-cursor: same arrival-order permutation, unique ranks).

#define K_DIM 128
#define SCAN_B 256        // elements per scan block
#define FIXP 1048576.0f   // 2^20 fixed-point scale for weighted degree

using half8   = __attribute__((ext_vector_type(8))) _Float16;
using floatx4 = __attribute__((ext_vector_type(4))) float;

// ---------------- CSR build ----------------

// one u64 atomic per edge: bits [40..) = count, [0..40) = sum(ew) * 2^20.
// atomicAdd's return value >> 40 = this edge's rank within its target node.
__global__ void degree_kernel(const int* __restrict__ col, const float* __restrict__ ew,
                              unsigned long long* __restrict__ packed,
                              int* __restrict__ rank, int E) {
    int e = blockIdx.x * blockDim.x + threadIdx.x;
    if (e < E) {
        int c = col[e];
        unsigned long long add = (1ULL << 40) +
            (unsigned long long)(ew[e] * FIXP + 0.5f);
        unsigned long long old = atomicAdd(&packed[c], add);
        rank[e] = (int)(old >> 40);
    }
}

// unpack: dinv[i] = rsqrt(degw + 1), cnt[i] = count
__global__ void dinv_kernel(const unsigned long long* __restrict__ packed,
                            float* __restrict__ dinv, int* __restrict__ cnt, int n) {
    int i = blockIdx.x * blockDim.x + threadIdx.x;
    if (i < n) {
        unsigned long long p = packed[i];
        float degw = (float)(p & 0xFFFFFFFFFFULL) * (1.0f / FIXP);
        dinv[i] = rsqrtf(degw + 1.0f);
        cnt[i] = (int)(p >> 40);
    }
}

// phase 1: per-block sum of (cnt[i]+1)
__global__ void block_reduce_kernel(const int* __restrict__ cnt, int* __restrict__ bsum, int n) {
    __shared__ int s[SCAN_B];
    const int t = threadIdx.x;
    const int i = blockIdx.x * SCAN_B + t;
    s[t] = (i < n) ? cnt[i] + 1 : 0;
    __syncthreads();
    for (int off = SCAN_B / 2; off > 0; off >>= 1) {
        if (t < off) s[t] += s[t + off];
        __syncthreads();
    }
    if (t == 0) bsum[blockIdx.x] = s[0];
}

// phase 2: single block, exclusive scan of nb (<=256) block sums in place
__global__ void bsum_scan_kernel(int* __restrict__ bsum, int nb) {
    __shared__ int s[SCAN_B];
    const int t = threadIdx.x;
    const int v = (t < nb) ? bsum[t] : 0;
    s[t] = v;
    __syncthreads();
    for (int off = 1; off < SCAN_B; off <<= 1) {
        int u = (t >= off) ? s[t - off] : 0;
        __syncthreads();
        s[t] += u;
        __syncthreads();
    }
    if (t < nb) bsum[t] = s[t] - v;   // exclusive
}

// phase 3: per-block exclusive scan + block prefix; write offs and the
// self-loop CSR entry (slot 0 of each node's segment, raw weight 1.0).
__global__ void scan_write_kernel(const int* __restrict__ cnt,
                                  const int* __restrict__ bsum,
                                  int* __restrict__ offs,
                                  int2* __restrict__ csr, int n) {
    __shared__ int s[SCAN_B];
    const int t = threadIdx.x;
    const int i = blockIdx.x * SCAN_B + t;
    const int v = (i < n) ? cnt[i] + 1 : 0;
    s[t] = v;
    __syncthreads();
    for (int off = 1; off < SCAN_B; off <<= 1) {
        int u = (t >= off) ? s[t - off] : 0;
        __syncthreads();
        s[t] += u;
        __syncthreads();
    }
    const int excl = s[t] - v + bsum[blockIdx.x];
    if (i < n) {
        offs[i] = excl;
        csr[excl] = make_int2(i, __float_as_int(1.0f));
        if (i == n - 1) offs[n] = excl + v; // = n + e
    }
}

// atomic-free scatter: pos = offs[col] + 1 + rank[e]
__global__ void fill_kernel(const int* __restrict__ row, const int* __restrict__ col,
                            const float* __restrict__ ew, const int* __restrict__ rank,
                            const int* __restrict__ offs, int2* __restrict__ csr, int E) {
    int e = blockIdx.x * blockDim.x + threadIdx.x;
    if (e < E) {
        int c = col[e];
        int pos = offs[c] + 1 + rank[e];
        csr[pos] = make_int2(row[e], __float_as_int(ew[e]));
    }
}

// convert W1|W2|W3 (fp32) -> contiguous fp16 buffer
__global__ void w2h_kernel(const float* __restrict__ W1, const float* __restrict__ W2,
                           const float* __restrict__ W3, __half* __restrict__ Wh,
                           int n1, int n2, int n3) {
    int i = blockIdx.x * blockDim.x + threadIdx.x;
    if (i >= n1 + n2 + n3) return;
    float v = (i < n1) ? W1[i] : (i < n1 + n2 ? W2[i - n1] : W3[i - n1 - n2]);
    Wh[i] = __float2half_rn(v);
}

// ---------------- MFMA GEMM: C[n][o] = half(dinv[n] * sum_k A[n][k] * W[o][k]) ----------------
// A: [nrows,128] (fp32 if FP32IN else fp16); Wh: [BN,128] fp16; C: [nrows,BN] fp16.
// 256 threads = 4 waves; wave handles 16 rows x BN cols; K=128 in 4 chunks of 32.

template <int BN, bool FP32IN>
__global__ __launch_bounds__(256) void mfma_gemm(const void* __restrict__ Ain,
                                                 const __half* __restrict__ Wh,
                                                 const float* __restrict__ dinv,
                                                 __half* __restrict__ C, int nrows) {
    constexpr int NT = BN / 16;
    const int wave = threadIdx.x >> 6;
    const int lane = threadIdx.x & 63;
    const int quad = lane >> 4;
    const int l16  = lane & 15;
    const int row0 = blockIdx.x * 64 + wave * 16;

    int arow = row0 + l16;
    if (arow > nrows - 1) arow = nrows - 1;

    floatx4 acc[NT] = {};

#pragma unroll
    for (int kc = 0; kc < 4; ++kc) {
        const int kof = kc * 32 + quad * 8;
        half8 af;
        if constexpr (FP32IN) {
            const float* ap = (const float*)Ain + (size_t)arow * K_DIM + kof;
            float4 f0 = *(const float4*)ap;
            float4 f1 = *(const float4*)(ap + 4);
            af[0] = (_Float16)f0.x; af[1] = (_Float16)f0.y;
            af[2] = (_Float16)f0.z; af[3] = (_Float16)f0.w;
            af[4] = (_Float16)f1.x; af[5] = (_Float16)f1.y;
            af[6] = (_Float16)f1.z; af[7] = (_Float16)f1.w;
        } else {
            af = *(const half8*)((const __half*)Ain + (size_t)arow * K_DIM + kof);
        }
#pragma unroll
        for (int ct = 0; ct < NT; ++ct) {
            half8 bf = *(const half8*)(Wh + (size_t)(ct * 16 + l16) * K_DIM + kof);
            acc[ct] = __builtin_amdgcn_mfma_f32_16x16x32_f16(af, bf, acc[ct], 0, 0, 0);
        }
    }

    // epilogue: D(row=quad*4+r, col=ct*16+l16)
    float dv[4];
    int grow[4];
    bool ok[4];
#pragma unroll
    for (int r = 0; r < 4; ++r) {
        grow[r] = row0 + quad * 4 + r;
        ok[r] = grow[r] < nrows;
        dv[r] = ok[r] ? dinv[grow[r]] : 0.f;
    }
#pragma unroll
    for (int ct = 0; ct < NT; ++ct) {
        const int colb = ct * 16 + l16;
#pragma unroll
        for (int r = 0; r < 4; ++r)
            if (ok[r])
                C[(size_t)grow[r] * BN + colb] = __float2half_rn(acc[ct][r] * dv[r]);
    }
}

// ---------------- aggregation: out[i] = relu(bias + dinv[i] * sum_e w_e * m[src_e]) ----------------
// R4 known-good form. m fp16. D=128: one wave per node, lane handles features
// (2l, 2l+1) via one __half2 load per row. D=64: half-wave per edge parity,
// shfl_xor(32) combine. OUT half or float.

template <int D, typename OUT>
__global__ __launch_bounds__(256) void agg_kernel(
    const __half* __restrict__ m, const int* __restrict__ offs,
    const int2* __restrict__ csr, const float* __restrict__ dinv,
    const float* __restrict__ bias, OUT* __restrict__ out, int n) {
    const int wid = threadIdx.x >> 6;
    const int lane = threadIdx.x & 63;
    const int node = (blockIdx.x << 2) + wid;
    if (node >= n) return;
    const int beg = offs[node];
    const int end = offs[node + 1];
    const __half2* mh = (const __half2*)m;   // row stride D/2 half2
    float acc0 = 0.f, acc1 = 0.f;

    if constexpr (D == 128) {
        int k = beg;
        for (; k + 4 <= end; k += 4) {
            int2 e0 = csr[k], e1 = csr[k + 1], e2 = csr[k + 2], e3 = csr[k + 3];
            float2 f0 = __half22float2(mh[(size_t)e0.x * 64 + lane]);
            float2 f1 = __half22float2(mh[(size_t)e1.x * 64 + lane]);
            float2 f2 = __half22float2(mh[(size_t)e2.x * 64 + lane]);
            float2 f3 = __half22float2(mh[(size_t)e3.x * 64 + lane]);
            float w0 = __int_as_float(e0.y), w1 = __int_as_float(e1.y);
            float w2 = __int_as_float(e2.y), w3 = __int_as_float(e3.y);
            acc0 = fmaf(w0, f0.x, acc0); acc1 = fmaf(w0, f0.y, acc1);
            acc0 = fmaf(w1, f1.x, acc0); acc1 = fmaf(w1, f1.y, acc1);
            acc0 = fmaf(w2, f2.x, acc0); acc1 = fmaf(w2, f2.y, acc1);
            acc0 = fmaf(w3, f3.x, acc0); acc1 = fmaf(w3, f3.y, acc1);
        }
        for (; k < end; ++k) {
            int2 e0 = csr[k];
            float w0 = __int_as_float(e0.y);
            float2 f0 = __half22float2(mh[(size_t)e0.x * 64 + lane]);
            acc0 = fmaf(w0, f0.x, acc0); acc1 = fmaf(w0, f0.y, acc1);
        }
        const float dv = dinv[node];
        const float2 bv = *(const float2*)(bias + 2 * lane);
        float ox = fmaxf(acc0 * dv + bv.x, 0.f);
        float oy = fmaxf(acc1 * dv + bv.y, 0.f);
        if constexpr (sizeof(OUT) == 2) {
            ((__half2*)out)[(size_t)node * 64 + lane] = __floats2half2_rn(ox, oy);
        } else {
            *(float2*)((float*)out + (size_t)node * 128 + 2 * lane) = make_float2(ox, oy);
        }
    } else {
        // D == 64: lanes 0-31 take even edges, 32-63 odd; feature pair (2sl, 2sl+1)
        const int half = lane >> 5;
        const int sl = lane & 31;
        int k = beg;
        for (; k + 8 <= end; k += 8) {
            int2 e0 = csr[k + half], e1 = csr[k + 2 + half];
            int2 e2 = csr[k + 4 + half], e3 = csr[k + 6 + half];
            float2 f0 = __half22float2(mh[(size_t)e0.x * 32 + sl]);
            float2 f1 = __half22float2(mh[(size_t)e1.x * 32 + sl]);
            float2 f2 = __half22float2(mh[(size_t)e2.x * 32 + sl]);
            float2 f3 = __half22float2(mh[(size_t)e3.x * 32 + sl]);
            float w0 = __int_as_float(e0.y), w1 = __int_as_float(e1.y);
            float w2 = __int_as_float(e2.y), w3 = __int_as_float(e3.y);
            acc0 = fmaf(w0, f0.x, acc0); acc1 = fmaf(w0, f0.y, acc1);
            acc0 = fmaf(w1, f1.x, acc0); acc1 = fmaf(w1, f1.y, acc1);
            acc0 = fmaf(w2, f2.x, acc0); acc1 = fmaf(w2, f2.y, acc1);
            acc0 = fmaf(w3, f3.x, acc0); acc1 = fmaf(w3, f3.y, acc1);
        }
        for (; k + 2 <= end; k += 2) {
            int2 e0 = csr[k + half];
            float w0 = __int_as_float(e0.y);
            float2 f0 = __half22float2(mh[(size_t)e0.x * 32 + sl]);
            acc0 = fmaf(w0, f0.x, acc0); acc1 = fmaf(w0, f0.y, acc1);
        }
        if (k < end && half == 0) {
            int2 e0 = csr[k];
            float w0 = __int_as_float(e0.y);
            float2 f0 = __half22float2(mh[(size_t)e0.x * 32 + sl]);
            acc0 = fmaf(w0, f0.x, acc0); acc1 = fmaf(w0, f0.y, acc1);
        }
        acc0 += __shfl_xor(acc0, 32);
        acc1 += __shfl_xor(acc1, 32);
        if (half == 0) {
            const float dv = dinv[node];
            const float2 bv = *(const float2*)(bias + 2 * sl);
            float ox = fmaxf(acc0 * dv + bv.x, 0.f);
            float oy = fmaxf(acc1 * dv + bv.y, 0.f);
            *(float2*)((float*)out + (size_t)node * 64 + 2 * sl) = make_float2(ox, oy);
        }
    }
}

// ---------------- launch ----------------

extern "C" void kernel_launch(void* const* d_in, const int* in_sizes, int n_in,
                              void* d_out, int out_size, void* d_ws, size_t ws_size,
                              hipStream_t stream) {
    const float* x  = (const float*)d_in[0];
    const int*   ei = (const int*)d_in[1];   // [2, E] int32
    const float* ew = (const float*)d_in[2];
    const float* W1 = (const float*)d_in[3];
    const float* b1 = (const float*)d_in[4];
    const float* W2 = (const float*)d_in[5];
    const float* b2 = (const float*)d_in[6];
    const float* W3 = (const float*)d_in[7];
    const float* b3 = (const float*)d_in[8];
    float* out = (float*)d_out;

    const int N = in_sizes[0] / K_DIM;      // 50000
    const int E = in_sizes[2];              // 800000
    const int* row = ei;                    // edge_index[0] (source)
    const int* col = ei + E;                // edge_index[1] (target / aggregation)

    const int nb = (N + SCAN_B - 1) / SCAN_B;   // scan blocks (196 <= 256)
    const int NW1 = 128 * 128, NW2 = 128 * 128, NW3 = 64 * 128;

    // workspace layout, 8B-aligned sections first
    unsigned long long* packed = (unsigned long long*)d_ws;    // N u64
    __half* m_buf = (__half*)(packed + N);                     // N*128 fp16
    __half* h_buf = m_buf + (size_t)N * K_DIM;                 // N*128 fp16
    __half* Wh    = h_buf + (size_t)N * K_DIM;                 // 40960 fp16
    int2*  csr    = (int2*)(Wh + NW1 + NW2 + NW3);             // N+E int2
    int*   offs   = (int*)(csr + (size_t)(N + E));             // N+1
    int*   rank   = offs + (N + 1);                            // E
    float* dinv   = (float*)(rank + E);                        // N
    int*   cnt    = (int*)(dinv + N);                          // N
    int*   bsum   = cnt + N;                                   // nb

    hipMemsetAsync(packed, 0, (size_t)N * sizeof(unsigned long long), stream);

    degree_kernel<<<(E + 255) / 256, 256, 0, stream>>>(col, ew, packed, rank, E);
    dinv_kernel<<<(N + 255) / 256, 256, 0, stream>>>(packed, dinv, cnt, N);
    block_reduce_kernel<<<nb, SCAN_B, 0, stream>>>(cnt, bsum, N);
    bsum_scan_kernel<<<1, SCAN_B, 0, stream>>>(bsum, nb);
    scan_write_kernel<<<nb, SCAN_B, 0, stream>>>(cnt, bsum, offs, csr, N);
    fill_kernel<<<(E + 255) / 256, 256, 0, stream>>>(row, col, ew, rank, offs, csr, E);
    w2h_kernel<<<(NW1 + NW2 + NW3 + 255) / 256, 256, 0, stream>>>(W1, W2, W3, Wh,
                                                                  NW1, NW2, NW3);

    const int gemm_blocks = (N + 63) / 64;
    const int agg_blocks = (N + 3) / 4;

    // layer 1: m = fp16(dinv * (x @ W1^T)) ; h = fp16(relu(dinv * agg(m) + b1))
    mfma_gemm<128, true><<<gemm_blocks, 256, 0, stream>>>(x, Wh, dinv, m_buf, N);
    agg_kernel<128, __half><<<agg_blocks, 256, 0, stream>>>(m_buf, offs, csr, dinv, b1, h_buf, N);
    // layer 2
    mfma_gemm<128, false><<<gemm_blocks, 256, 0, stream>>>(h_buf, Wh + NW1, dinv, m_buf, N);
    agg_kernel<128, __half><<<agg_blocks, 256, 0, stream>>>(m_buf, offs, csr, dinv, b2, h_buf, N);
    // layer 3: F_OUT=64, write d_out (fp32) directly
    mfma_gemm<64, false><<<gemm_blocks, 256, 0, stream>>>(h_buf, Wh + NW1 + NW2, dinv, m_buf, N);
    agg_kernel<64, float><<<agg_blocks, 256, 0, stream>>>(m_buf, offs, csr, dinv, b3, out, N);
}